// Round 2
// baseline (1852.971 us; speedup 1.0000x reference)
//
#include <hip/hip_runtime.h>
#include <hip/hip_bf16.h>

#define DIM 768
#define SEQ 2048
#define BATCH 2
#define HEADS 12
#define HD 64
#define DFF 3072
#define COND 128
#define ADA6 4608
#define TOKENS 4096  // BATCH*SEQ

// ---------------- ada = c @ ada_w + ada_b  (2 x 4608) ----------------
__global__ void ada_kernel(const float* __restrict__ c, const float* __restrict__ ada_w,
                           const float* __restrict__ ada_b, float* __restrict__ ada) {
    int j = blockIdx.x * 256 + threadIdx.x;
    int bb = blockIdx.y;
    if (j < ADA6) {
        float acc = ada_b[j];
        for (int k = 0; k < COND; ++k)
            acc = fmaf(c[bb * COND + k], ada_w[(long)k * ADA6 + j], acc);
        ada[bb * ADA6 + j] = acc;
    }
}

// ---------------- layernorm + adaLN modulate ----------------
__global__ __launch_bounds__(256) void ln_mod_kernel(const float* __restrict__ x,
                                                     const float* __restrict__ w,
                                                     const float* __restrict__ ada,
                                                     int shiftOff, int scaleOff,
                                                     float* __restrict__ out) {
    int token = blockIdx.x;
    int bb = token >> 11;
    int tid = threadIdx.x;
    const float* xi = x + (long)token * DIM;
    float v[3];
    float sum = 0.f, sumsq = 0.f;
    for (int t = 0; t < 3; ++t) {
        float val = xi[tid + 256 * t];
        v[t] = val;
        sum += val;
        sumsq = fmaf(val, val, sumsq);
    }
    for (int msk = 1; msk < 64; msk <<= 1) {
        sum += __shfl_xor(sum, msk, 64);
        sumsq += __shfl_xor(sumsq, msk, 64);
    }
    __shared__ float red0[4], red1[4];
    int wave = tid >> 6;
    if ((tid & 63) == 0) { red0[wave] = sum; red1[wave] = sumsq; }
    __syncthreads();
    sum = red0[0] + red0[1] + red0[2] + red0[3];
    sumsq = red1[0] + red1[1] + red1[2] + red1[3];
    float mu = sum * (1.f / DIM);
    float var = sumsq * (1.f / DIM) - mu * mu;
    float rs = rsqrtf(var + 1e-5f);
    const float* sh = ada + bb * ADA6 + shiftOff;
    const float* sc = ada + bb * ADA6 + scaleOff;
    float* oi = out + (long)token * DIM;
    for (int t = 0; t < 3; ++t) {
        int j = tid + 256 * t;
        oi[j] = (v[t] - mu) * rs * w[j] * (1.f + sc[j]) + sh[j];
    }
}

// ---------------- generic tiled fp32 GEMM with epilogues ----------------
// C[M][N] = A[M][K] @ B[K][N]
// EPI 0: store; 1: gelu(acc+bias); 2: gate*acc+skip; 3: gate*(acc+bias)+skip
template <int EPI>
__global__ __launch_bounds__(256) void gemm_f32(const float* __restrict__ A,
                                                const float* __restrict__ B,
                                                float* __restrict__ C, int M, int N, int K,
                                                const float* __restrict__ bias,
                                                const float* __restrict__ gate,
                                                const float* __restrict__ skip) {
    __shared__ float As[16][65];
    __shared__ float Bs[16][65];
    int bm = blockIdx.y, bn = blockIdx.x;
    int tid = threadIdx.x;
    int tx = tid & 15, ty = tid >> 4;
    float acc[4][4] = {};
    int row0 = bm * 64, col0 = bn * 64;
    for (int k0 = 0; k0 < K; k0 += 16) {
        for (int t = 0; t < 4; ++t) {
            int l = tid + 256 * t;
            int rr = l >> 4, kk = l & 15;
            As[kk][rr] = A[(long)(row0 + rr) * K + k0 + kk];
        }
        for (int t = 0; t < 4; ++t) {
            int l = tid + 256 * t;
            int kk = l >> 6, jj = l & 63;
            Bs[kk][jj] = B[(long)(k0 + kk) * N + col0 + jj];
        }
        __syncthreads();
        for (int kk = 0; kk < 16; ++kk) {
            float a[4], bv[4];
            for (int i = 0; i < 4; ++i) a[i] = As[kk][ty * 4 + i];
            for (int j = 0; j < 4; ++j) bv[j] = Bs[kk][tx * 4 + j];
            for (int i = 0; i < 4; ++i)
                for (int j = 0; j < 4; ++j) acc[i][j] = fmaf(a[i], bv[j], acc[i][j]);
        }
        __syncthreads();
    }
    for (int i = 0; i < 4; ++i) {
        long m = row0 + ty * 4 + i;
        int bb = (int)(m >> 11);
        for (int j = 0; j < 4; ++j) {
            int n = col0 + tx * 4 + j;
            float v = acc[i][j];
            if (EPI == 1) {
                v += bias[n];
                float t = 0.7978845608028654f * (v + 0.044715f * v * v * v);
                v = 0.5f * v * (1.f + tanhf(t));
            } else if (EPI == 2) {
                v = gate[bb * ADA6 + n] * v + skip[m * DIM + n];
            } else if (EPI == 3) {
                v = gate[bb * ADA6 + n] * (v + bias[n]) + skip[m * DIM + n];
            }
            C[m * N + n] = v;
        }
    }
}

// ---------------- RoPE in-place over all of q,k,v ----------------
__global__ void rope_kernel(float* __restrict__ qkv, const float* __restrict__ cosT,
                            const float* __restrict__ sinT) {
    long idx = (long)blockIdx.x * 256 + threadIdx.x;  // TOKENS * 36 * 32
    if (idx >= (long)TOKENS * 1152) return;
    int token = (int)(idx / 1152);
    int rem = (int)(idx % 1152);
    int g = rem >> 5;
    int d = rem & 31;
    int pos = token & 1023;
    float cv = cosT[pos * HD + d];
    float sv = sinT[pos * HD + d];
    long base = (long)token * 2304 + g * 64;
    float v0 = qkv[base + d];
    float v1 = qkv[base + d + 32];
    qkv[base + d] = v0 * cv - v1 * sv;
    qkv[base + d + 32] = v1 * cv + v0 * sv;
}

// ---------------- flash attention with the block-diff mask ----------------
// grid (128 qblocks, 12 heads, 2 batch), 256 threads.
//   qb < 64:  kv = [qb*16, qb*16+16) U [1024, 1024+qb*16)
//   qb >= 64: kv = [1024, 1024+(qb-63)*16)
__global__ __launch_bounds__(256) void attn_kernel(const float* __restrict__ qkv,
                                                   float* __restrict__ o) {
    int qb = blockIdx.x;
    int head = blockIdx.y;
    int bb = blockIdx.z;
    int tid = threadIdx.x;
    int r = tid >> 4;  // q row 0..15
    int c = tid & 15;
    __shared__ float qs[16][65];
    __shared__ float ks[64][65];
    __shared__ float vs[64][65];
    __shared__ float ps[16][64];
    const long row0 = (long)bb * SEQ + qb * 16;
    const int qcol = head * HD;
    const int kcol = DIM + head * HD;
    const int vcol = 2 * DIM + head * HD;
    {
        // 16 rows x 64 cols = 256 float4
        int rr = tid >> 4, d4 = (tid & 15) * 4;
        float4 qv = *(const float4*)&qkv[(row0 + rr) * 2304 + qcol + d4];
        qs[rr][d4 + 0] = qv.x; qs[rr][d4 + 1] = qv.y;
        qs[rr][d4 + 2] = qv.z; qs[rr][d4 + 3] = qv.w;
    }
    float m_run = -3.0e38f, l_run = 0.f;
    float oacc[4] = {0.f, 0.f, 0.f, 0.f};
    int nseg = (qb < 64) ? 2 : 1;
    for (int seg = 0; seg < nseg; ++seg) {
        int start, len;
        if (qb < 64) {
            if (seg == 0) { start = qb * 16; len = 16; }
            else          { start = 1024;   len = qb * 16; }
        } else {
            start = 1024; len = (qb - 63) * 16;
        }
        for (int ck = 0; ck < len; ck += 64) {
            int cl = min(64, len - ck);
            __syncthreads();  // previous chunk fully consumed
            // 64 rows x 64 cols = 1024 float4 -> 4 passes
            for (int t = 0; t < 4; ++t) {
                int item = tid + 256 * t;          // 0..1023
                int rr = item >> 4;                 // 0..63
                int d4 = (item & 15) * 4;
                if (rr < cl) {
                    long krow = (long)bb * SEQ + start + ck + rr;
                    float4 kv = *(const float4*)&qkv[krow * 2304 + kcol + d4];
                    ks[rr][d4 + 0] = kv.x; ks[rr][d4 + 1] = kv.y;
                    ks[rr][d4 + 2] = kv.z; ks[rr][d4 + 3] = kv.w;
                    float4 vv = *(const float4*)&qkv[krow * 2304 + vcol + d4];
                    vs[rr][d4 + 0] = vv.x; vs[rr][d4 + 1] = vv.y;
                    vs[rr][d4 + 2] = vv.z; vs[rr][d4 + 3] = vv.w;
                } else {
                    ks[rr][d4 + 0] = 0.f; ks[rr][d4 + 1] = 0.f;
                    ks[rr][d4 + 2] = 0.f; ks[rr][d4 + 3] = 0.f;
                    vs[rr][d4 + 0] = 0.f; vs[rr][d4 + 1] = 0.f;
                    vs[rr][d4 + 2] = 0.f; vs[rr][d4 + 3] = 0.f;
                }
            }
            __syncthreads();
            float s[4];
            float mloc = -3.0e38f;
            for (int cc = 0; cc < 4; ++cc) {
                int col = c + cc * 16;
                float acc = 0.f;
                for (int d = 0; d < 64; ++d) acc = fmaf(qs[r][d], ks[col][d], acc);
                acc *= 0.125f;
                if (col >= cl) acc = -3.0e38f;
                s[cc] = acc;
                mloc = fmaxf(mloc, acc);
            }
            for (int msk = 1; msk < 16; msk <<= 1) mloc = fmaxf(mloc, __shfl_xor(mloc, msk, 16));
            float m_new = fmaxf(m_run, mloc);
            float scale = __expf(m_run - m_new);
            float psum = 0.f;
            for (int cc = 0; cc < 4; ++cc) {
                float p = __expf(s[cc] - m_new);  // masked cols underflow to 0
                ps[r][c + cc * 16] = p;
                psum += p;
            }
            for (int msk = 1; msk < 16; msk <<= 1) psum += __shfl_xor(psum, msk, 16);
            l_run = l_run * scale + psum;
            m_run = m_new;
            __syncthreads();
            for (int k4 = 0; k4 < 4; ++k4) oacc[k4] *= scale;
            for (int j = 0; j < 64; ++j) {
                float pj = ps[r][j];
                for (int k4 = 0; k4 < 4; ++k4)
                    oacc[k4] = fmaf(pj, vs[j][c + 16 * k4], oacc[k4]);
            }
        }
    }
    float inv = 1.f / l_run;
    for (int k4 = 0; k4 < 4; ++k4)
        o[(row0 + r) * DIM + head * HD + c + 16 * k4] = oacc[k4] * inv;
}

extern "C" void kernel_launch(void* const* d_in, const int* in_sizes, int n_in,
                              void* d_out, int out_size, void* d_ws, size_t ws_size,
                              hipStream_t stream) {
    const float* x      = (const float*)d_in[0];
    const float* cosT   = (const float*)d_in[1];
    const float* sinT   = (const float*)d_in[2];
    const float* c      = (const float*)d_in[3];
    const float* W_qkv  = (const float*)d_in[4];
    const float* W_out  = (const float*)d_in[5];
    const float* ln1_w  = (const float*)d_in[6];
    const float* ln2_w  = (const float*)d_in[7];
    const float* mlp_w1 = (const float*)d_in[8];
    const float* mlp_b1 = (const float*)d_in[9];
    const float* mlp_w2 = (const float*)d_in[10];
    const float* mlp_b2 = (const float*)d_in[11];
    const float* ada_w  = (const float*)d_in[12];
    const float* ada_b  = (const float*)d_in[13];
    float* out = (float*)d_out;

    char* ws = (char*)d_ws;
    float* ada  = (float*)(ws);                       // 36 KB
    float* qkv  = (float*)(ws + (1L << 16));          // 37.75 MB
    float* buf0 = (float*)(ws + (1L << 16) + 37748736L);              // 12.6 MB
    float* x1   = (float*)(ws + (1L << 16) + 37748736L + 12582912L);  // 12.6 MB
    float* a1   = (float*)(ws + (1L << 16) + 37748736L + 2 * 12582912L);  // 50.3 MB
    float* o    = a1;

    ada_kernel<<<dim3(18, 2), 256, 0, stream>>>(c, ada_w, ada_b, ada);
    ln_mod_kernel<<<TOKENS, 256, 0, stream>>>(x, ln1_w, ada, 0, 768, buf0);
    gemm_f32<0><<<dim3(36, 64), 256, 0, stream>>>(buf0, W_qkv, qkv, TOKENS, 2304, DIM,
                                                  nullptr, nullptr, nullptr);
    {
        long total = (long)TOKENS * 1152;
        rope_kernel<<<(int)((total + 255) / 256), 256, 0, stream>>>(qkv, cosT, sinT);
    }
    attn_kernel<<<dim3(128, HEADS, BATCH), 256, 0, stream>>>(qkv, o);
    gemm_f32<2><<<dim3(12, 64), 256, 0, stream>>>(o, W_out, x1, TOKENS, DIM, DIM,
                                                  nullptr, ada + 1536, x);
    ln_mod_kernel<<<TOKENS, 256, 0, stream>>>(x1, ln2_w, ada, 2304, 3072, buf0);
    gemm_f32<1><<<dim3(48, 64), 256, 0, stream>>>(buf0, mlp_w1, a1, TOKENS, DFF, DIM,
                                                  mlp_b1, nullptr, nullptr);
    gemm_f32<3><<<dim3(12, 64), 256, 0, stream>>>(a1, mlp_w2, out, TOKENS, DIM, DFF,
                                                  mlp_b2, ada + 3840, x1);
}

// Round 3
// 403.261 us; speedup vs baseline: 4.5950x; 4.5950x over previous
//
#include <hip/hip_runtime.h>
#include <hip/hip_bf16.h>
#include <stdint.h>

#define DIM 768
#define SEQ 2048
#define TOKENS 4096
#define HEADS 12
#define DFF 3072
#define COND 128
#define ADA6 4608

typedef __attribute__((ext_vector_type(8))) short bf16x8;
typedef __attribute__((ext_vector_type(4))) float f32x4;

#define MFMA16x32(a, b, c) __builtin_amdgcn_mfma_f32_16x16x32_bf16(a, b, c, 0, 0, 0)
#define GLDS16(g, l)                                                                  \
    __builtin_amdgcn_global_load_lds((const __attribute__((address_space(1))) void*)(g), \
                                     (__attribute__((address_space(3))) void*)(l), 16, 0, 0)

__device__ __forceinline__ ushort f2bf(float f) {
    union { float f; uint32_t u; } v;
    v.f = f;
    uint32_t r = v.u + 0x7FFF + ((v.u >> 16) & 1);
    return (ushort)(r >> 16);
}

// ---------------- ada = c @ ada_w + ada_b  (2 x 4608, fp32) ----------------
__global__ void ada_kernel(const float* __restrict__ c, const float* __restrict__ ada_w,
                           const float* __restrict__ ada_b, float* __restrict__ ada) {
    int j = blockIdx.x * 256 + threadIdx.x;
    int bb = blockIdx.y;
    if (j < ADA6) {
        float acc = ada_b[j];
        for (int k = 0; k < COND; ++k)
            acc = fmaf(c[bb * COND + k], ada_w[(long)k * ADA6 + j], acc);
        ada[bb * ADA6 + j] = acc;
    }
}

// ------------- weight convert + transpose: W[K][N] f32 -> Wt[N][K] bf16 -------------
__global__ __launch_bounds__(256) void convT(const float* __restrict__ W,
                                             ushort* __restrict__ Wt, int K, int N) {
    __shared__ float t[64][65];
    int tid = threadIdx.x;
    int n0 = blockIdx.x * 64, k0 = blockIdx.y * 64;
#pragma unroll
    for (int it = 0; it < 4; ++it) {
        int idx = it * 256 + tid;
        int kr = idx >> 4, nc = (idx & 15) * 4;
        float4 v = *(const float4*)&W[(long)(k0 + kr) * N + n0 + nc];
        t[kr][nc] = v.x; t[kr][nc + 1] = v.y; t[kr][nc + 2] = v.z; t[kr][nc + 3] = v.w;
    }
    __syncthreads();
#pragma unroll
    for (int it = 0; it < 4; ++it) {
        int idx = it * 256 + tid;
        int nr = idx >> 4, kc = (idx & 15) * 4;
        ushort4 v;
        v.x = f2bf(t[kc][nr]); v.y = f2bf(t[kc + 1][nr]);
        v.z = f2bf(t[kc + 2][nr]); v.w = f2bf(t[kc + 3][nr]);
        *(ushort4*)&Wt[(long)(n0 + nr) * K + k0 + kc] = v;
    }
}

// ---------------- layernorm + adaLN modulate -> bf16 ----------------
__global__ __launch_bounds__(256) void ln_mod_kernel(const float* __restrict__ x,
                                                     const float* __restrict__ w,
                                                     const float* __restrict__ ada,
                                                     int shiftOff, int scaleOff,
                                                     ushort* __restrict__ out) {
    int token = blockIdx.x;
    int bb = token >> 11;
    int tid = threadIdx.x;
    const float* xi = x + (long)token * DIM;
    float v[3];
    float sum = 0.f, sumsq = 0.f;
#pragma unroll
    for (int t = 0; t < 3; ++t) {
        float val = xi[tid + 256 * t];
        v[t] = val;
        sum += val;
        sumsq = fmaf(val, val, sumsq);
    }
    for (int msk = 1; msk < 64; msk <<= 1) {
        sum += __shfl_xor(sum, msk, 64);
        sumsq += __shfl_xor(sumsq, msk, 64);
    }
    __shared__ float red0[4], red1[4];
    int wave = tid >> 6;
    if ((tid & 63) == 0) { red0[wave] = sum; red1[wave] = sumsq; }
    __syncthreads();
    sum = red0[0] + red0[1] + red0[2] + red0[3];
    sumsq = red1[0] + red1[1] + red1[2] + red1[3];
    float mu = sum * (1.f / DIM);
    float var = sumsq * (1.f / DIM) - mu * mu;
    float rs = rsqrtf(var + 1e-5f);
    const float* sh = ada + bb * ADA6 + shiftOff;
    const float* sc = ada + bb * ADA6 + scaleOff;
    ushort* oi = out + (long)token * DIM;
#pragma unroll
    for (int t = 0; t < 3; ++t) {
        int j = tid + 256 * t;
        oi[j] = f2bf((v[t] - mu) * rs * w[j] * (1.f + sc[j]) + sh[j]);
    }
}

// ---------------- bf16 MFMA GEMM, 128x128 tile, BK=64, 4 waves ----------------
// A[M][K] bf16 row-major, B = Wt[N][K] bf16 row-major.  C = A @ Wt^T.
// EPI 0: rope -> bf16 (qkv)        (uses cosT/sinT)
// EPI 1: gate*acc + skip -> f32    (x1)
// EPI 2: gelu(acc+bias) -> bf16    (a1)
// EPI 3: gate*(acc+bias)+skip ->f32 (out)
template <int EPI>
__global__ __launch_bounds__(256) void gemm_bf16(const ushort* __restrict__ A,
                                                 const ushort* __restrict__ B,
                                                 void* __restrict__ Cp, int M, int N, int K,
                                                 const float* __restrict__ bias,
                                                 const float* __restrict__ gate,
                                                 const float* __restrict__ skip,
                                                 const float* __restrict__ cosT,
                                                 const float* __restrict__ sinT) {
    __shared__ ushort As[128 * 64];
    __shared__ ushort Bs[128 * 64];
    const int tid = threadIdx.x;
    const int wave = tid >> 6, lane = tid & 63;
    const int lo = lane & 15, hi = lane >> 4;
    const int wr = wave >> 1, wc = wave & 1;
    const int row0 = blockIdx.y * 128, col0 = blockIdx.x * 128;
    const int srow = tid >> 3;       // 0..31
    const int scol = (tid & 7) * 8;  // k elems
    f32x4 acc[4][4] = {};
    const long astep = (long)32 * K;
    const ushort* Ag = A + (long)(row0 + srow) * K + scol;
    const ushort* Bg = B + (long)(col0 + srow) * K + scol;
    for (int k0 = 0; k0 < K; k0 += 64) {
        __syncthreads();
#pragma unroll
        for (int t = 0; t < 4; ++t)
            GLDS16(Ag + t * astep + k0, (char*)As + (t * 256 + tid) * 16);
#pragma unroll
        for (int t = 0; t < 4; ++t)
            GLDS16(Bg + t * astep + k0, (char*)Bs + (t * 256 + tid) * 16);
        __syncthreads();
#pragma unroll
        for (int kk = 0; kk < 2; ++kk) {
            bf16x8 af[4], bfr[4];
#pragma unroll
            for (int m = 0; m < 4; ++m)
                af[m] = *(const bf16x8*)&As[(wr * 64 + m * 16 + lo) * 64 + kk * 32 + hi * 8];
#pragma unroll
            for (int n = 0; n < 4; ++n)
                bfr[n] = *(const bf16x8*)&Bs[(wc * 64 + n * 16 + lo) * 64 + kk * 32 + hi * 8];
#pragma unroll
            for (int m = 0; m < 4; ++m)
#pragma unroll
                for (int n = 0; n < 4; ++n)
                    acc[m][n] = MFMA16x32(af[m], bfr[n], acc[m][n]);
        }
    }
    // epilogue: lane holds C[row0+wr*64+m*16+hi*4+reg][col0+wc*64+n*16+lo]
    if (EPI == 0) {
        ushort* C = (ushort*)Cp;
#pragma unroll
        for (int m = 0; m < 4; ++m)
#pragma unroll
            for (int reg = 0; reg < 4; ++reg) {
                int r = row0 + wr * 64 + m * 16 + hi * 4 + reg;
                int pos = r & 1023;
                const float* cb = cosT + pos * 64;
                const float* sb = sinT + pos * 64;
                long rb = (long)r * N + col0 + wc * 64;
#pragma unroll
                for (int pr = 0; pr < 2; ++pr) {
                    int i = pr * 16 + lo;
                    float v0 = acc[m][pr][reg], v1 = acc[m][pr + 2][reg];
                    float c0 = cb[i], s0 = sb[i], c1 = cb[i + 32], s1 = sb[i + 32];
                    C[rb + i] = f2bf(v0 * c0 - v1 * s0);
                    C[rb + i + 32] = f2bf(v1 * c1 + v0 * s1);
                }
            }
    } else if (EPI == 1) {
        float* C = (float*)Cp;
#pragma unroll
        for (int m = 0; m < 4; ++m)
#pragma unroll
            for (int reg = 0; reg < 4; ++reg) {
                int r = row0 + wr * 64 + m * 16 + hi * 4 + reg;
                int bbi = r >> 11;
#pragma unroll
                for (int n = 0; n < 4; ++n) {
                    int c = col0 + wc * 64 + n * 16 + lo;
                    C[(long)r * N + c] =
                        gate[bbi * ADA6 + c] * acc[m][n][reg] + skip[(long)r * DIM + c];
                }
            }
    } else if (EPI == 2) {
        ushort* C = (ushort*)Cp;
#pragma unroll
        for (int m = 0; m < 4; ++m)
#pragma unroll
            for (int reg = 0; reg < 4; ++reg) {
                int r = row0 + wr * 64 + m * 16 + hi * 4 + reg;
#pragma unroll
                for (int n = 0; n < 4; ++n) {
                    int c = col0 + wc * 64 + n * 16 + lo;
                    float v = acc[m][n][reg] + bias[c];
                    float g = v / (1.f + __expf(-1.5957691216f * (v + 0.044715f * v * v * v)));
                    C[(long)r * N + c] = f2bf(g);
                }
            }
    } else {
        float* C = (float*)Cp;
#pragma unroll
        for (int m = 0; m < 4; ++m)
#pragma unroll
            for (int reg = 0; reg < 4; ++reg) {
                int r = row0 + wr * 64 + m * 16 + hi * 4 + reg;
                int bbi = r >> 11;
#pragma unroll
                for (int n = 0; n < 4; ++n) {
                    int c = col0 + wc * 64 + n * 16 + lo;
                    C[(long)r * N + c] = gate[bbi * ADA6 + c] * (acc[m][n][reg] + bias[c]) +
                                         skip[(long)r * DIM + c];
                }
            }
    }
}

// ------------- V transpose: qkv[tok][1536+h*64+d] -> vt[(bb*12+h)*64+d][tok] -------------
__global__ __launch_bounds__(256) void vtrans(const ushort* __restrict__ qkv,
                                              ushort* __restrict__ vt) {
    __shared__ ushort t[64][65];
    int tid = threadIdx.x;
    int tb = blockIdx.x;    // token block 0..31
    int head = blockIdx.y;  // 0..11
    int bb = blockIdx.z;
#pragma unroll
    for (int it = 0; it < 4; ++it) {
        int idx = it * 256 + tid;
        int tok = idx >> 4, d4 = (idx & 15) * 4;
        const ushort* p = qkv + ((long)bb * SEQ + tb * 64 + tok) * 2304 + 1536 + head * 64 + d4;
        ushort4 v = *(const ushort4*)p;
        t[tok][d4] = v.x; t[tok][d4 + 1] = v.y; t[tok][d4 + 2] = v.z; t[tok][d4 + 3] = v.w;
    }
    __syncthreads();
#pragma unroll
    for (int it = 0; it < 4; ++it) {
        int idx = it * 256 + tid;
        int d = idx >> 4, t4 = (idx & 15) * 4;
        ushort4 v;
        v.x = t[t4][d]; v.y = t[t4 + 1][d]; v.z = t[t4 + 2][d]; v.w = t[t4 + 3][d];
        *(ushort4*)&vt[((long)(bb * HEADS + head) * 64 + d) * SEQ + tb * 64 + t4] = v;
    }
}

// ---------------- MFMA flash attention, 1 wave = 1 head, no K/V staging ----------------
// grid (128 qblocks, 3 headgroups, 2 batch), 256 thr; wave w -> head = hg*4+w.
//   qb < 64:  kv = [qb*16, qb*16+16) U [1024, 1024+qb*16)
//   qb >= 64: kv = [1024, 1024+(qb-63)*16)
__global__ __launch_bounds__(256) void attn_mfma(const ushort* __restrict__ qkv,
                                                 const ushort* __restrict__ vt,
                                                 ushort* __restrict__ o) {
    __shared__ char ps[4 * 2048];
    const int tid = threadIdx.x;
    const int wave = tid >> 6, lane = tid & 63;
    const int lo = lane & 15, hi = lane >> 4;
    const int qb = blockIdx.x;
    const int head = blockIdx.y * 4 + wave;
    const int bb = blockIdx.z;
    char* psb = ps + wave * 2048;
    const long row0 = (long)bb * SEQ + qb * 16;
    const ushort* Qp = qkv + (row0 + lo) * 2304 + head * 64 + hi * 8;
    bf16x8 qf0 = *(const bf16x8*)Qp;
    bf16x8 qf1 = *(const bf16x8*)(Qp + 32);
    f32x4 oacc[4] = {};
    float m_run[4], l_run[4];
#pragma unroll
    for (int g = 0; g < 4; ++g) { m_run[g] = -3.0e38f; l_run[g] = 0.f; }
    int nseg = (qb < 64) ? 2 : 1;
    for (int seg = 0; seg < nseg; ++seg) {
        int start, len;
        if (qb < 64) {
            if (seg == 0) { start = qb * 16; len = 16; }
            else          { start = 1024;   len = qb * 16; }
        } else {
            start = 1024; len = (qb - 63) * 16;
        }
        for (int ck = 0; ck < len; ck += 64) {
            int cl = min(64, len - ck);
            const long kr0 = (long)bb * SEQ + start + ck;
            f32x4 s[4];
#pragma unroll
            for (int n = 0; n < 4; ++n) {
                const ushort* Kp = qkv + (kr0 + n * 16 + lo) * 2304 + DIM + head * 64 + hi * 8;
                bf16x8 kf0 = *(const bf16x8*)Kp;
                bf16x8 kf1 = *(const bf16x8*)(Kp + 32);
                f32x4 z = {};
                z = MFMA16x32(qf0, kf0, z);
                z = MFMA16x32(qf1, kf1, z);
                s[n] = z;
            }
            float p[4][4], mx[4], scl[4], sm[4];
#pragma unroll
            for (int g = 0; g < 4; ++g) mx[g] = -3.0e38f;
#pragma unroll
            for (int n = 0; n < 4; ++n)
#pragma unroll
                for (int g = 0; g < 4; ++g) {
                    float v = s[n][g] * 0.125f;
                    if (lo + n * 16 >= cl) v = -3.0e38f;
                    p[n][g] = v;
                    mx[g] = fmaxf(mx[g], v);
                }
#pragma unroll
            for (int msk = 1; msk < 16; msk <<= 1)
#pragma unroll
                for (int g = 0; g < 4; ++g) mx[g] = fmaxf(mx[g], __shfl_xor(mx[g], msk, 64));
#pragma unroll
            for (int g = 0; g < 4; ++g) {
                float mn = fmaxf(m_run[g], mx[g]);
                scl[g] = __expf(m_run[g] - mn);
                m_run[g] = mn;
                sm[g] = 0.f;
            }
#pragma unroll
            for (int n = 0; n < 4; ++n)
#pragma unroll
                for (int g = 0; g < 4; ++g) {
                    float e = __expf(p[n][g] - m_run[g]);
                    p[n][g] = e;
                    sm[g] += e;
                }
#pragma unroll
            for (int msk = 1; msk < 16; msk <<= 1)
#pragma unroll
                for (int g = 0; g < 4; ++g) sm[g] += __shfl_xor(sm[g], msk, 64);
            f32x4 sclv;
#pragma unroll
            for (int g = 0; g < 4; ++g) {
                l_run[g] = l_run[g] * scl[g] + sm[g];
                sclv[g] = scl[g];
            }
#pragma unroll
            for (int d = 0; d < 4; ++d) oacc[d] *= sclv;
            // P (D-layout) -> LDS, XOR-swizzled, as A-operand layout
            asm volatile("s_waitcnt lgkmcnt(0)" ::: "memory");
#pragma unroll
            for (int n = 0; n < 4; ++n)
#pragma unroll
                for (int g = 0; g < 4; ++g) {
                    int q = hi * 4 + g, key = lo + n * 16;
                    *(ushort*)(psb + q * 128 + (((key >> 3) ^ (q & 7)) << 4) +
                               ((key & 7) << 1)) = f2bf(p[n][g]);
                }
            asm volatile("s_waitcnt lgkmcnt(0)" ::: "memory");
            bf16x8 pa0 = *(const bf16x8*)(psb + lo * 128 + ((hi ^ (lo & 7)) << 4));
            bf16x8 pa1 = *(const bf16x8*)(psb + lo * 128 + (((4 + hi) ^ (lo & 7)) << 4));
#pragma unroll
            for (int d = 0; d < 4; ++d) {
                const ushort* Vp =
                    vt + ((long)(bb * HEADS + head) * 64 + d * 16 + lo) * SEQ + start + ck + hi * 8;
                bf16x8 v0 = *(const bf16x8*)Vp;
                bf16x8 v1 = *(const bf16x8*)(Vp + 32);
                oacc[d] = MFMA16x32(pa0, v0, oacc[d]);
                oacc[d] = MFMA16x32(pa1, v1, oacc[d]);
            }
        }
    }
#pragma unroll
    for (int d = 0; d < 4; ++d)
#pragma unroll
        for (int g = 0; g < 4; ++g)
            o[(row0 + hi * 4 + g) * DIM + head * 64 + d * 16 + lo] =
                f2bf(oacc[d][g] * (1.f / l_run[g]));
}

extern "C" void kernel_launch(void* const* d_in, const int* in_sizes, int n_in,
                              void* d_out, int out_size, void* d_ws, size_t ws_size,
                              hipStream_t stream) {
    const float* x      = (const float*)d_in[0];
    const float* cosT   = (const float*)d_in[1];
    const float* sinT   = (const float*)d_in[2];
    const float* c      = (const float*)d_in[3];
    const float* W_qkv  = (const float*)d_in[4];
    const float* W_out  = (const float*)d_in[5];
    const float* ln1_w  = (const float*)d_in[6];
    const float* ln2_w  = (const float*)d_in[7];
    const float* mlp_w1 = (const float*)d_in[8];
    const float* mlp_b1 = (const float*)d_in[9];
    const float* mlp_w2 = (const float*)d_in[10];
    const float* mlp_b2 = (const float*)d_in[11];
    const float* ada_w  = (const float*)d_in[12];
    const float* ada_b  = (const float*)d_in[13];
    float* out = (float*)d_out;

    char* ws = (char*)d_ws;
    float*  ada   = (float*)(ws + 0);
    ushort* h     = (ushort*)(ws + 65536L);
    ushort* qkv   = (ushort*)(ws + 6356992L);
    ushort* vt    = (ushort*)(ws + 25231360L);
    ushort* o     = (ushort*)(ws + 31522816L);
    float*  x1    = (float*)(ws + 37814272L);
    ushort* a1    = (ushort*)(ws + 50397184L);
    ushort* wqkvT = (ushort*)(ws + 75563008L);
    ushort* woutT = (ushort*)(ws + 79101952L);
    ushort* w1T   = (ushort*)(ws + 80281600L);
    ushort* w2T   = (ushort*)(ws + 85000192L);

    ada_kernel<<<dim3(18, 2), 256, 0, stream>>>(c, ada_w, ada_b, ada);
    convT<<<dim3(36, 12), 256, 0, stream>>>(W_qkv, wqkvT, 768, 2304);
    convT<<<dim3(12, 12), 256, 0, stream>>>(W_out, woutT, 768, 768);
    convT<<<dim3(48, 12), 256, 0, stream>>>(mlp_w1, w1T, 768, 3072);
    convT<<<dim3(12, 48), 256, 0, stream>>>(mlp_w2, w2T, 3072, 768);

    ln_mod_kernel<<<TOKENS, 256, 0, stream>>>(x, ln1_w, ada, 0, 768, h);
    gemm_bf16<0><<<dim3(18, 32), 256, 0, stream>>>(h, wqkvT, qkv, TOKENS, 2304, 768,
                                                   nullptr, nullptr, nullptr, cosT, sinT);
    vtrans<<<dim3(32, 12, 2), 256, 0, stream>>>(qkv, vt);
    attn_mfma<<<dim3(128, 3, 2), 256, 0, stream>>>(qkv, vt, o);
    gemm_bf16<1><<<dim3(6, 32), 256, 0, stream>>>(o, woutT, x1, TOKENS, 768, 768,
                                                  nullptr, ada + 1536, x, nullptr, nullptr);
    ln_mod_kernel<<<TOKENS, 256, 0, stream>>>(x1, ln2_w, ada, 2304, 3072, h);
    gemm_bf16<2><<<dim3(24, 32), 256, 0, stream>>>(h, w1T, a1, TOKENS, DFF, 768,
                                                   mlp_b1, nullptr, nullptr, nullptr, nullptr);
    gemm_bf16<3><<<dim3(6, 32), 256, 0, stream>>>(a1, w2T, out, TOKENS, 768, DFF,
                                                  mlp_b2, ada + 3840, x1, nullptr, nullptr);
}

// Round 4
// 398.826 us; speedup vs baseline: 4.6461x; 1.0111x over previous
//
#include <hip/hip_runtime.h>
#include <hip/hip_bf16.h>
#include <stdint.h>

#define DIM 768
#define SEQ 2048
#define TOKENS 4096
#define HEADS 12
#define DFF 3072
#define COND 128
#define ADA6 4608

typedef __attribute__((ext_vector_type(8))) short bf16x8;
typedef __attribute__((ext_vector_type(4))) float f32x4;

#define MFMA16x32(a, b, c) __builtin_amdgcn_mfma_f32_16x16x32_bf16(a, b, c, 0, 0, 0)
#define GLDS16(g, l)                                                                  \
    __builtin_amdgcn_global_load_lds((const __attribute__((address_space(1))) void*)(g), \
                                     (__attribute__((address_space(3))) void*)(l), 16, 0, 0)

__device__ __forceinline__ ushort f2bf(float f) {
    union { float f; uint32_t u; } v;
    v.f = f;
    uint32_t r = v.u + 0x7FFF + ((v.u >> 16) & 1);
    return (ushort)(r >> 16);
}

__device__ __forceinline__ uint32_t packbf2(float a, float b) {
    union { __hip_bfloat162 h; uint32_t u; } cv;
    cv.h = __float22bfloat162_rn(make_float2(a, b));
    return cv.u;
}

// ---------------- ada = c @ ada_w + ada_b  (2 x 4608, fp32) ----------------
__global__ void ada_kernel(const float* __restrict__ c, const float* __restrict__ ada_w,
                           const float* __restrict__ ada_b, float* __restrict__ ada) {
    int j = blockIdx.x * 256 + threadIdx.x;
    int bb = blockIdx.y;
    if (j < ADA6) {
        float acc = ada_b[j];
        for (int k = 0; k < COND; ++k)
            acc = fmaf(c[bb * COND + k], ada_w[(long)k * ADA6 + j], acc);
        ada[bb * ADA6 + j] = acc;
    }
}

// ------------- weight convert + transpose: W[K][N] f32 -> Wt[N][K] bf16 -------------
__global__ __launch_bounds__(256) void convT(const float* __restrict__ W,
                                             ushort* __restrict__ Wt, int K, int N) {
    __shared__ float t[64][65];
    int tid = threadIdx.x;
    int n0 = blockIdx.x * 64, k0 = blockIdx.y * 64;
#pragma unroll
    for (int it = 0; it < 4; ++it) {
        int idx = it * 256 + tid;
        int kr = idx >> 4, nc = (idx & 15) * 4;
        float4 v = *(const float4*)&W[(long)(k0 + kr) * N + n0 + nc];
        t[kr][nc] = v.x; t[kr][nc + 1] = v.y; t[kr][nc + 2] = v.z; t[kr][nc + 3] = v.w;
    }
    __syncthreads();
#pragma unroll
    for (int it = 0; it < 4; ++it) {
        int idx = it * 256 + tid;
        int nr = idx >> 4, kc = (idx & 15) * 4;
        ushort4 v;
        v.x = f2bf(t[kc][nr]); v.y = f2bf(t[kc + 1][nr]);
        v.z = f2bf(t[kc + 2][nr]); v.w = f2bf(t[kc + 3][nr]);
        *(ushort4*)&Wt[(long)(n0 + nr) * K + k0 + kc] = v;
    }
}

// ---------------- layernorm + adaLN modulate -> bf16 ----------------
__global__ __launch_bounds__(256) void ln_mod_kernel(const float* __restrict__ x,
                                                     const float* __restrict__ w,
                                                     const float* __restrict__ ada,
                                                     int shiftOff, int scaleOff,
                                                     ushort* __restrict__ out) {
    int token = blockIdx.x;
    int bb = token >> 11;
    int tid = threadIdx.x;
    const float* xi = x + (long)token * DIM;
    float v[3];
    float sum = 0.f, sumsq = 0.f;
#pragma unroll
    for (int t = 0; t < 3; ++t) {
        float val = xi[tid + 256 * t];
        v[t] = val;
        sum += val;
        sumsq = fmaf(val, val, sumsq);
    }
    for (int msk = 1; msk < 64; msk <<= 1) {
        sum += __shfl_xor(sum, msk, 64);
        sumsq += __shfl_xor(sumsq, msk, 64);
    }
    __shared__ float red0[4], red1[4];
    int wave = tid >> 6;
    if ((tid & 63) == 0) { red0[wave] = sum; red1[wave] = sumsq; }
    __syncthreads();
    sum = red0[0] + red0[1] + red0[2] + red0[3];
    sumsq = red1[0] + red1[1] + red1[2] + red1[3];
    float mu = sum * (1.f / DIM);
    float var = sumsq * (1.f / DIM) - mu * mu;
    float rs = rsqrtf(var + 1e-5f);
    const float* sh = ada + bb * ADA6 + shiftOff;
    const float* sc = ada + bb * ADA6 + scaleOff;
    ushort* oi = out + (long)token * DIM;
#pragma unroll
    for (int t = 0; t < 3; ++t) {
        int j = tid + 256 * t;
        oi[j] = f2bf((v[t] - mu) * rs * w[j] * (1.f + sc[j]) + sh[j]);
    }
}

// ---------------- bf16 MFMA GEMM, 128x128 tile, BK=64, 4 waves ----------------
// A[M][K] bf16 row-major, B = Wt[N][K] bf16 row-major.  C = A @ Wt^T.
// EPI 0: rope -> bf16 (qkv); 1: gate*acc+skip -> f32; 2: gelu(acc+bias) -> bf16;
// EPI 3: gate*(acc+bias)+skip -> f32
template <int EPI>
__global__ __launch_bounds__(256) void gemm_bf16(const ushort* __restrict__ A,
                                                 const ushort* __restrict__ B,
                                                 void* __restrict__ Cp, int M, int N, int K,
                                                 const float* __restrict__ bias,
                                                 const float* __restrict__ gate,
                                                 const float* __restrict__ skip,
                                                 const float* __restrict__ cosT,
                                                 const float* __restrict__ sinT) {
    __shared__ ushort As[128 * 64];
    __shared__ ushort Bs[128 * 64];
    const int tid = threadIdx.x;
    const int wave = tid >> 6, lane = tid & 63;
    const int lo = lane & 15, hi = lane >> 4;
    const int wr = wave >> 1, wc = wave & 1;
    const int row0 = blockIdx.y * 128, col0 = blockIdx.x * 128;
    const int srow = tid >> 3;       // 0..31
    const int scol = (tid & 7) * 8;  // k elems
    f32x4 acc[4][4] = {};
    const long astep = (long)32 * K;
    const ushort* Ag = A + (long)(row0 + srow) * K + scol;
    const ushort* Bg = B + (long)(col0 + srow) * K + scol;
    for (int k0 = 0; k0 < K; k0 += 64) {
        __syncthreads();
#pragma unroll
        for (int t = 0; t < 4; ++t)
            GLDS16(Ag + t * astep + k0, (char*)As + (t * 256 + tid) * 16);
#pragma unroll
        for (int t = 0; t < 4; ++t)
            GLDS16(Bg + t * astep + k0, (char*)Bs + (t * 256 + tid) * 16);
        __syncthreads();
#pragma unroll
        for (int kk = 0; kk < 2; ++kk) {
            bf16x8 af[4], bfr[4];
#pragma unroll
            for (int m = 0; m < 4; ++m)
                af[m] = *(const bf16x8*)&As[(wr * 64 + m * 16 + lo) * 64 + kk * 32 + hi * 8];
#pragma unroll
            for (int n = 0; n < 4; ++n)
                bfr[n] = *(const bf16x8*)&Bs[(wc * 64 + n * 16 + lo) * 64 + kk * 32 + hi * 8];
#pragma unroll
            for (int m = 0; m < 4; ++m)
#pragma unroll
                for (int n = 0; n < 4; ++n)
                    acc[m][n] = MFMA16x32(af[m], bfr[n], acc[m][n]);
        }
    }
    // epilogue: lane holds C[row0+wr*64+m*16+hi*4+reg][col0+wc*64+n*16+lo]
    if (EPI == 0) {
        ushort* C = (ushort*)Cp;
#pragma unroll
        for (int m = 0; m < 4; ++m)
#pragma unroll
            for (int reg = 0; reg < 4; ++reg) {
                int r = row0 + wr * 64 + m * 16 + hi * 4 + reg;
                int pos = r & 1023;
                const float* cb = cosT + pos * 64;
                const float* sb = sinT + pos * 64;
                long rb = (long)r * N + col0 + wc * 64;
#pragma unroll
                for (int pr = 0; pr < 2; ++pr) {
                    int i = pr * 16 + lo;
                    float v0 = acc[m][pr][reg], v1 = acc[m][pr + 2][reg];
                    float c0 = cb[i], s0 = sb[i], c1 = cb[i + 32], s1 = sb[i + 32];
                    C[rb + i] = f2bf(v0 * c0 - v1 * s0);
                    C[rb + i + 32] = f2bf(v1 * c1 + v0 * s1);
                }
            }
    } else if (EPI == 1) {
        float* C = (float*)Cp;
#pragma unroll
        for (int m = 0; m < 4; ++m)
#pragma unroll
            for (int reg = 0; reg < 4; ++reg) {
                int r = row0 + wr * 64 + m * 16 + hi * 4 + reg;
                int bbi = r >> 11;
#pragma unroll
                for (int n = 0; n < 4; ++n) {
                    int c = col0 + wc * 64 + n * 16 + lo;
                    C[(long)r * N + c] =
                        gate[bbi * ADA6 + c] * acc[m][n][reg] + skip[(long)r * DIM + c];
                }
            }
    } else if (EPI == 2) {
        ushort* C = (ushort*)Cp;
#pragma unroll
        for (int m = 0; m < 4; ++m)
#pragma unroll
            for (int reg = 0; reg < 4; ++reg) {
                int r = row0 + wr * 64 + m * 16 + hi * 4 + reg;
#pragma unroll
                for (int n = 0; n < 4; ++n) {
                    int c = col0 + wc * 64 + n * 16 + lo;
                    float v = acc[m][n][reg] + bias[c];
                    float g = v / (1.f + __expf(-1.5957691216f * (v + 0.044715f * v * v * v)));
                    C[(long)r * N + c] = f2bf(g);
                }
            }
    } else {
        float* C = (float*)Cp;
#pragma unroll
        for (int m = 0; m < 4; ++m)
#pragma unroll
            for (int reg = 0; reg < 4; ++reg) {
                int r = row0 + wr * 64 + m * 16 + hi * 4 + reg;
                int bbi = r >> 11;
#pragma unroll
                for (int n = 0; n < 4; ++n) {
                    int c = col0 + wc * 64 + n * 16 + lo;
                    C[(long)r * N + c] = gate[bbi * ADA6 + c] * (acc[m][n][reg] + bias[c]) +
                                         skip[(long)r * DIM + c];
                }
            }
    }
}

// ------------- V transpose: qkv[tok][1536+h*64+d] -> vt[(bb*12+h)*64+d][tok] -------------
__global__ __launch_bounds__(256) void vtrans(const ushort* __restrict__ qkv,
                                              ushort* __restrict__ vt) {
    __shared__ ushort t[64][65];
    int tid = threadIdx.x;
    int tb = blockIdx.x;
    int head = blockIdx.y;
    int bb = blockIdx.z;
#pragma unroll
    for (int it = 0; it < 4; ++it) {
        int idx = it * 256 + tid;
        int tok = idx >> 4, d4 = (idx & 15) * 4;
        const ushort* p = qkv + ((long)bb * SEQ + tb * 64 + tok) * 2304 + 1536 + head * 64 + d4;
        ushort4 v = *(const ushort4*)p;
        t[tok][d4] = v.x; t[tok][d4 + 1] = v.y; t[tok][d4 + 2] = v.z; t[tok][d4 + 3] = v.w;
    }
    __syncthreads();
#pragma unroll
    for (int it = 0; it < 4; ++it) {
        int idx = it * 256 + tid;
        int d = idx >> 4, t4 = (idx & 15) * 4;
        ushort4 v;
        v.x = t[t4][d]; v.y = t[t4 + 1][d]; v.z = t[t4 + 2][d]; v.w = t[t4 + 3][d];
        *(ushort4*)&vt[((long)(bb * HEADS + head) * 64 + d) * SEQ + tb * 64 + t4] = v;
    }
}

// ---------------- MFMA flash attention, swapped operands ----------------
// grid (128, 3, 2), 256 thr; wave w -> head = hg*4+w; heavy-first qb order.
// QK^T computed as mfma(K, Q): lane (lo,hi) holds S[key=n*16+hi*4+reg][q=lo]
// -> per-lane scalar row softmax (q = lo), reduce across hi via shfl 16/32.
// PV computed as mfma(Vt, P): lane holds O[d=dt*16+hi*4+reg][q=lo].
//   qb < 64:  kv = [qb*16, qb*16+16) U [1024, 1024+qb*16)
//   qb >= 64: kv = [1024, 1024+(qb-63)*16)
__global__ __launch_bounds__(256) void attn_mfma(const ushort* __restrict__ qkv,
                                                 const ushort* __restrict__ vt,
                                                 ushort* __restrict__ o) {
    __shared__ char ps[4 * 2048];
    const int tid = threadIdx.x;
    const int wave = tid >> 6, lane = tid & 63;
    const int lo = lane & 15, hi = lane >> 4;
    const int bx = blockIdx.x;
    const int qb = (bx & 1) ? (63 - (bx >> 1)) : (127 - (bx >> 1));  // heavy first
    const int head = blockIdx.y * 4 + wave;
    const int bb = blockIdx.z;
    char* psb = ps + wave * 2048;
    const int swz = (lo & 7) << 4;
    const long row0 = (long)bb * SEQ + qb * 16;
    const ushort* Qp = qkv + (row0 + lo) * 2304 + head * 64 + hi * 8;
    bf16x8 qf0 = *(const bf16x8*)Qp;
    bf16x8 qf1 = *(const bf16x8*)(Qp + 32);
    f32x4 oacc[4] = {};
    float m_run = -3.0e38f, l_run = 0.f;
    const ushort* Vbase = vt + (long)(bb * HEADS + head) * 64 * SEQ;
    int nseg = (qb < 64) ? 2 : 1;
    for (int seg = 0; seg < nseg; ++seg) {
        int start, len;
        if (qb < 64) {
            if (seg == 0) { start = qb * 16; len = 16; }
            else          { start = 1024;   len = qb * 16; }
        } else {
            start = 1024; len = (qb - 63) * 16;
        }
        for (int ck = 0; ck < len; ck += 64) {
            int cl = min(64, len - ck);  // multiple of 16
            const long kr0 = (long)bb * SEQ + start + ck;
            f32x4 s[4] = {};
#pragma unroll
            for (int n = 0; n < 4; ++n) {
                if (n * 16 < cl) {
                    const ushort* Kp =
                        qkv + (kr0 + n * 16 + lo) * 2304 + DIM + head * 64 + hi * 8;
                    bf16x8 kf0 = *(const bf16x8*)Kp;
                    bf16x8 kf1 = *(const bf16x8*)(Kp + 32);
                    f32x4 z = {};
                    z = MFMA16x32(kf0, qf0, z);
                    z = MFMA16x32(kf1, qf1, z);
                    s[n] = z;
                }
            }
            // row softmax: each lane owns q = lo; its 16 S values are keys
            // n*16 + hi*4 + reg.  Reduce across the 4 hi lanes.
            float p[4][4];
            float mx = -3.0e38f;
#pragma unroll
            for (int n = 0; n < 4; ++n)
#pragma unroll
                for (int g = 0; g < 4; ++g) {
                    float v = (n * 16 < cl) ? s[n][g] * 0.125f : -3.0e38f;
                    p[n][g] = v;
                    mx = fmaxf(mx, v);
                }
            mx = fmaxf(mx, __shfl_xor(mx, 16, 64));
            mx = fmaxf(mx, __shfl_xor(mx, 32, 64));
            float m_new = fmaxf(m_run, mx);
            float scale = __expf(m_run - m_new);
            float psum = 0.f;
#pragma unroll
            for (int n = 0; n < 4; ++n)
#pragma unroll
                for (int g = 0; g < 4; ++g) {
                    float e = __expf(p[n][g] - m_new);
                    p[n][g] = e;
                    psum += e;
                }
            psum += __shfl_xor(psum, 16, 64);
            psum += __shfl_xor(psum, 32, 64);
            l_run = l_run * scale + psum;
            m_run = m_new;
#pragma unroll
            for (int dt = 0; dt < 4; ++dt) oacc[dt] *= scale;
            // P -> bf16 pairs -> LDS row q=lo (128B rows, XOR-swizzled)
#pragma unroll
            for (int n = 0; n < 4; ++n)
#pragma unroll
                for (int pr = 0; pr < 2; ++pr) {
                    uint32_t u = packbf2(p[n][pr * 2], p[n][pr * 2 + 1]);
                    *(uint32_t*)(psb + lo * 128 + ((n * 32 + hi * 8 + pr * 4) ^ swz)) = u;
                }
            bf16x8 pa0 = *(const bf16x8*)(psb + lo * 128 + ((hi * 16) ^ swz));
            bf16x8 pa1 = *(const bf16x8*)(psb + lo * 128 + ((64 + hi * 16) ^ swz));
#pragma unroll
            for (int dt = 0; dt < 4; ++dt) {
                const ushort* Vp = Vbase + (long)(dt * 16 + lo) * SEQ + start + ck + hi * 8;
                bf16x8 v0 = *(const bf16x8*)Vp;
                oacc[dt] = MFMA16x32(v0, pa0, oacc[dt]);
                if (cl > 32) {
                    bf16x8 v1 = *(const bf16x8*)(Vp + 32);
                    oacc[dt] = MFMA16x32(v1, pa1, oacc[dt]);
                }
            }
        }
    }
    float inv = 1.f / l_run;
#pragma unroll
    for (int dt = 0; dt < 4; ++dt) {
        ushort4 st;
        st.x = f2bf(oacc[dt][0] * inv);
        st.y = f2bf(oacc[dt][1] * inv);
        st.z = f2bf(oacc[dt][2] * inv);
        st.w = f2bf(oacc[dt][3] * inv);
        *(ushort4*)&o[(row0 + lo) * DIM + head * 64 + dt * 16 + hi * 4] = st;
    }
}

extern "C" void kernel_launch(void* const* d_in, const int* in_sizes, int n_in,
                              void* d_out, int out_size, void* d_ws, size_t ws_size,
                              hipStream_t stream) {
    const float* x      = (const float*)d_in[0];
    const float* cosT   = (const float*)d_in[1];
    const float* sinT   = (const float*)d_in[2];
    const float* c      = (const float*)d_in[3];
    const float* W_qkv  = (const float*)d_in[4];
    const float* W_out  = (const float*)d_in[5];
    const float* ln1_w  = (const float*)d_in[6];
    const float* ln2_w  = (const float*)d_in[7];
    const float* mlp_w1 = (const float*)d_in[8];
    const float* mlp_b1 = (const float*)d_in[9];
    const float* mlp_w2 = (const float*)d_in[10];
    const float* mlp_b2 = (const float*)d_in[11];
    const float* ada_w  = (const float*)d_in[12];
    const float* ada_b  = (const float*)d_in[13];
    float* out = (float*)d_out;

    char* ws = (char*)d_ws;
    float*  ada   = (float*)(ws + 0);
    ushort* h     = (ushort*)(ws + 65536L);
    ushort* qkv   = (ushort*)(ws + 6356992L);
    ushort* vt    = (ushort*)(ws + 25231360L);
    ushort* o     = (ushort*)(ws + 31522816L);
    float*  x1    = (float*)(ws + 37814272L);
    ushort* a1    = (ushort*)(ws + 50397184L);
    ushort* wqkvT = (ushort*)(ws + 75563008L);
    ushort* woutT = (ushort*)(ws + 79101952L);
    ushort* w1T   = (ushort*)(ws + 80281600L);
    ushort* w2T   = (ushort*)(ws + 85000192L);

    ada_kernel<<<dim3(18, 2), 256, 0, stream>>>(c, ada_w, ada_b, ada);
    convT<<<dim3(36, 12), 256, 0, stream>>>(W_qkv, wqkvT, 768, 2304);
    convT<<<dim3(12, 12), 256, 0, stream>>>(W_out, woutT, 768, 768);
    convT<<<dim3(48, 12), 256, 0, stream>>>(mlp_w1, w1T, 768, 3072);
    convT<<<dim3(12, 48), 256, 0, stream>>>(mlp_w2, w2T, 3072, 768);

    ln_mod_kernel<<<TOKENS, 256, 0, stream>>>(x, ln1_w, ada, 0, 768, h);
    gemm_bf16<0><<<dim3(18, 32), 256, 0, stream>>>(h, wqkvT, qkv, TOKENS, 2304, 768,
                                                   nullptr, nullptr, nullptr, cosT, sinT);
    vtrans<<<dim3(32, 12, 2), 256, 0, stream>>>(qkv, vt);
    attn_mfma<<<dim3(128, 3, 2), 256, 0, stream>>>(qkv, vt, o);
    gemm_bf16<1><<<dim3(6, 32), 256, 0, stream>>>(o, woutT, x1, TOKENS, 768, 768,
                                                  nullptr, ada + 1536, x, nullptr, nullptr);
    ln_mod_kernel<<<TOKENS, 256, 0, stream>>>(x1, ln2_w, ada, 2304, 3072, h);
    gemm_bf16<2><<<dim3(24, 32), 256, 0, stream>>>(h, w1T, a1, TOKENS, DFF, 768,
                                                   mlp_b1, nullptr, nullptr, nullptr, nullptr);
    gemm_bf16<3><<<dim3(6, 32), 256, 0, stream>>>(a1, w2T, out, TOKENS, 768, DFF,
                                                  mlp_b2, ada + 3840, x1, nullptr, nullptr);
}

// Round 5
// 354.751 us; speedup vs baseline: 5.2233x; 1.1242x over previous
//
#include <hip/hip_runtime.h>
#include <hip/hip_bf16.h>
#include <stdint.h>

#define DIM 768
#define SEQ 2048
#define TOKENS 4096
#define HEADS 12
#define DFF 3072
#define COND 128
#define ADA6 4608

typedef __attribute__((ext_vector_type(8))) short bf16x8;
typedef __attribute__((ext_vector_type(4))) float f32x4;

#define MFMA16x32(a, b, c) __builtin_amdgcn_mfma_f32_16x16x32_bf16(a, b, c, 0, 0, 0)
#define GLDS16(g, l)                                                                  \
    __builtin_amdgcn_global_load_lds((const __attribute__((address_space(1))) void*)(g), \
                                     (__attribute__((address_space(3))) void*)(l), 16, 0, 0)

__device__ __forceinline__ ushort f2bf(float f) {
    union { float f; uint32_t u; } v;
    v.f = f;
    uint32_t r = v.u + 0x7FFF + ((v.u >> 16) & 1);
    return (ushort)(r >> 16);
}

__device__ __forceinline__ uint32_t packbf2(float a, float b) {
    union { __hip_bfloat162 h; uint32_t u; } cv;
    cv.h = __float22bfloat162_rn(make_float2(a, b));
    return cv.u;
}

// ---------------- ada = c @ ada_w + ada_b  (2 x 4608, fp32) ----------------
__global__ void ada_kernel(const float* __restrict__ c, const float* __restrict__ ada_w,
                           const float* __restrict__ ada_b, float* __restrict__ ada) {
    int j = blockIdx.x * 256 + threadIdx.x;
    int bb = blockIdx.y;
    if (j < ADA6) {
        float acc = ada_b[j];
        for (int k = 0; k < COND; ++k)
            acc = fmaf(c[bb * COND + k], ada_w[(long)k * ADA6 + j], acc);
        ada[bb * ADA6 + j] = acc;
    }
}

// ------------- weight convert + transpose: W[K][N] f32 -> Wt[N][K] bf16 -------------
__global__ __launch_bounds__(256) void convT(const float* __restrict__ W,
                                             ushort* __restrict__ Wt, int K, int N) {
    __shared__ float t[64][65];
    int tid = threadIdx.x;
    int n0 = blockIdx.x * 64, k0 = blockIdx.y * 64;
#pragma unroll
    for (int it = 0; it < 4; ++it) {
        int idx = it * 256 + tid;
        int kr = idx >> 4, nc = (idx & 15) * 4;
        float4 v = *(const float4*)&W[(long)(k0 + kr) * N + n0 + nc];
        t[kr][nc] = v.x; t[kr][nc + 1] = v.y; t[kr][nc + 2] = v.z; t[kr][nc + 3] = v.w;
    }
    __syncthreads();
#pragma unroll
    for (int it = 0; it < 4; ++it) {
        int idx = it * 256 + tid;
        int nr = idx >> 4, kc = (idx & 15) * 4;
        ushort4 v;
        v.x = f2bf(t[kc][nr]); v.y = f2bf(t[kc + 1][nr]);
        v.z = f2bf(t[kc + 2][nr]); v.w = f2bf(t[kc + 3][nr]);
        *(ushort4*)&Wt[(long)(n0 + nr) * K + k0 + kc] = v;
    }
}

// ---------------- layernorm + adaLN modulate -> bf16 ----------------
__global__ __launch_bounds__(256) void ln_mod_kernel(const float* __restrict__ x,
                                                     const float* __restrict__ w,
                                                     const float* __restrict__ ada,
                                                     int shiftOff, int scaleOff,
                                                     ushort* __restrict__ out) {
    int token = blockIdx.x;
    int bb = token >> 11;
    int tid = threadIdx.x;
    const float* xi = x + (long)token * DIM;
    float v[3];
    float sum = 0.f, sumsq = 0.f;
#pragma unroll
    for (int t = 0; t < 3; ++t) {
        float val = xi[tid + 256 * t];
        v[t] = val;
        sum += val;
        sumsq = fmaf(val, val, sumsq);
    }
    for (int msk = 1; msk < 64; msk <<= 1) {
        sum += __shfl_xor(sum, msk, 64);
        sumsq += __shfl_xor(sumsq, msk, 64);
    }
    __shared__ float red0[4], red1[4];
    int wave = tid >> 6;
    if ((tid & 63) == 0) { red0[wave] = sum; red1[wave] = sumsq; }
    __syncthreads();
    sum = red0[0] + red0[1] + red0[2] + red0[3];
    sumsq = red1[0] + red1[1] + red1[2] + red1[3];
    float mu = sum * (1.f / DIM);
    float var = sumsq * (1.f / DIM) - mu * mu;
    float rs = rsqrtf(var + 1e-5f);
    const float* sh = ada + bb * ADA6 + shiftOff;
    const float* sc = ada + bb * ADA6 + scaleOff;
    ushort* oi = out + (long)token * DIM;
#pragma unroll
    for (int t = 0; t < 3; ++t) {
        int j = tid + 256 * t;
        oi[j] = f2bf((v[t] - mu) * rs * w[j] * (1.f + sc[j]) + sh[j]);
    }
}

// ---------------- bf16 MFMA GEMM, BMx128 tile, BK=64, 4 waves ----------------
// A[M][K] bf16 row-major, B = Wt[N][K] bf16 row-major.  C = A @ Wt^T.
// EPI 0: rope -> bf16 (qkv); 1: gate*acc+skip -> f32; 2: gelu(acc+bias) -> bf16;
// EPI 3: gate*(acc+bias)+skip -> f32
template <int EPI, int BM>
__global__ __launch_bounds__(256) void gemm_bf16(const ushort* __restrict__ A,
                                                 const ushort* __restrict__ B,
                                                 void* __restrict__ Cp, int M, int N, int K,
                                                 const float* __restrict__ bias,
                                                 const float* __restrict__ gate,
                                                 const float* __restrict__ skip,
                                                 const float* __restrict__ cosT,
                                                 const float* __restrict__ sinT) {
    constexpr int MR = BM / 32;  // frags per wave in M
    __shared__ ushort As[BM * 64];
    __shared__ ushort Bs[128 * 64];
    const int tid = threadIdx.x;
    const int wave = tid >> 6, lane = tid & 63;
    const int lo = lane & 15, hi = lane >> 4;
    const int wr = wave >> 1, wc = wave & 1;
    const int row0 = blockIdx.y * BM, col0 = blockIdx.x * 128;
    const int srow = tid >> 3;       // 0..31
    const int scol = (tid & 7) * 8;  // k elems
    f32x4 acc[MR][4] = {};
    const long astep = (long)32 * K;
    const ushort* Ag = A + (long)(row0 + srow) * K + scol;
    const ushort* Bg = B + (long)(col0 + srow) * K + scol;
    for (int k0 = 0; k0 < K; k0 += 64) {
        __syncthreads();
#pragma unroll
        for (int t = 0; t < MR; ++t)
            GLDS16(Ag + t * astep + k0, (char*)As + (t * 256 + tid) * 16);
#pragma unroll
        for (int t = 0; t < 4; ++t)
            GLDS16(Bg + t * astep + k0, (char*)Bs + (t * 256 + tid) * 16);
        __syncthreads();
#pragma unroll
        for (int kk = 0; kk < 2; ++kk) {
            bf16x8 af[MR], bfr[4];
#pragma unroll
            for (int m = 0; m < MR; ++m)
                af[m] = *(const bf16x8*)&As[(wr * (BM / 2) + m * 16 + lo) * 64 + kk * 32 + hi * 8];
#pragma unroll
            for (int n = 0; n < 4; ++n)
                bfr[n] = *(const bf16x8*)&Bs[(wc * 64 + n * 16 + lo) * 64 + kk * 32 + hi * 8];
#pragma unroll
            for (int m = 0; m < MR; ++m)
#pragma unroll
                for (int n = 0; n < 4; ++n)
                    acc[m][n] = MFMA16x32(af[m], bfr[n], acc[m][n]);
        }
    }
    // epilogue: lane holds C[row0+wr*(BM/2)+m*16+hi*4+reg][col0+wc*64+n*16+lo]
    if (EPI == 0) {
        ushort* C = (ushort*)Cp;
#pragma unroll
        for (int m = 0; m < MR; ++m)
#pragma unroll
            for (int reg = 0; reg < 4; ++reg) {
                int r = row0 + wr * (BM / 2) + m * 16 + hi * 4 + reg;
                int pos = r & 1023;
                const float* cb = cosT + pos * 64;
                const float* sb = sinT + pos * 64;
                long rb = (long)r * N + col0 + wc * 64;
#pragma unroll
                for (int pr = 0; pr < 2; ++pr) {
                    int i = pr * 16 + lo;
                    float v0 = acc[m][pr][reg], v1 = acc[m][pr + 2][reg];
                    float c0 = cb[i], s0 = sb[i], c1 = cb[i + 32], s1 = sb[i + 32];
                    C[rb + i] = f2bf(v0 * c0 - v1 * s0);
                    C[rb + i + 32] = f2bf(v1 * c1 + v0 * s1);
                }
            }
    } else if (EPI == 1) {
        float* C = (float*)Cp;
#pragma unroll
        for (int m = 0; m < MR; ++m)
#pragma unroll
            for (int reg = 0; reg < 4; ++reg) {
                int r = row0 + wr * (BM / 2) + m * 16 + hi * 4 + reg;
                int bbi = r >> 11;
#pragma unroll
                for (int n = 0; n < 4; ++n) {
                    int c = col0 + wc * 64 + n * 16 + lo;
                    C[(long)r * N + c] =
                        gate[bbi * ADA6 + c] * acc[m][n][reg] + skip[(long)r * DIM + c];
                }
            }
    } else if (EPI == 2) {
        ushort* C = (ushort*)Cp;
#pragma unroll
        for (int m = 0; m < MR; ++m)
#pragma unroll
            for (int reg = 0; reg < 4; ++reg) {
                int r = row0 + wr * (BM / 2) + m * 16 + hi * 4 + reg;
#pragma unroll
                for (int n = 0; n < 4; ++n) {
                    int c = col0 + wc * 64 + n * 16 + lo;
                    float v = acc[m][n][reg] + bias[c];
                    float g = v / (1.f + __expf(-1.5957691216f * (v + 0.044715f * v * v * v)));
                    C[(long)r * N + c] = f2bf(g);
                }
            }
    } else {
        float* C = (float*)Cp;
#pragma unroll
        for (int m = 0; m < MR; ++m)
#pragma unroll
            for (int reg = 0; reg < 4; ++reg) {
                int r = row0 + wr * (BM / 2) + m * 16 + hi * 4 + reg;
                int bbi = r >> 11;
#pragma unroll
                for (int n = 0; n < 4; ++n) {
                    int c = col0 + wc * 64 + n * 16 + lo;
                    C[(long)r * N + c] = gate[bbi * ADA6 + c] * (acc[m][n][reg] + bias[c]) +
                                         skip[(long)r * DIM + c];
                }
            }
    }
}

// ------------- V transpose: qkv[tok][1536+h*64+d] -> vt[(bb*12+h)*64+d][tok] -------------
__global__ __launch_bounds__(256) void vtrans(const ushort* __restrict__ qkv,
                                              ushort* __restrict__ vt) {
    __shared__ ushort t[64][65];
    int tid = threadIdx.x;
    int tb = blockIdx.x;
    int head = blockIdx.y;
    int bb = blockIdx.z;
#pragma unroll
    for (int it = 0; it < 4; ++it) {
        int idx = it * 256 + tid;
        int tok = idx >> 4, d4 = (idx & 15) * 4;
        const ushort* p = qkv + ((long)bb * SEQ + tb * 64 + tok) * 2304 + 1536 + head * 64 + d4;
        ushort4 v = *(const ushort4*)p;
        t[tok][d4] = v.x; t[tok][d4 + 1] = v.y; t[tok][d4 + 2] = v.z; t[tok][d4 + 3] = v.w;
    }
    __syncthreads();
#pragma unroll
    for (int it = 0; it < 4; ++it) {
        int idx = it * 256 + tid;
        int d = idx >> 4, t4 = (idx & 15) * 4;
        ushort4 v;
        v.x = t[t4][d]; v.y = t[t4 + 1][d]; v.z = t[t4 + 2][d]; v.w = t[t4 + 3][d];
        *(ushort4*)&vt[((long)(bb * HEADS + head) * 64 + d) * SEQ + tb * 64 + t4] = v;
    }
}

// ---------------- MFMA flash attention, split-KV across 4 waves ----------------
// grid (128 qb, 12 heads, 2 bb), 256 thr. All 4 waves share (qb, head); each
// handles a strided subset of 64-key chunks of the second-half run; wave 3
// also takes the 16-key diagonal block (qb<64). Partials (m,l,o) merged via LDS.
// QK^T as mfma(K,Q): lane (lo,hi) holds S[key=n*16+hi*4+reg][q=lo].
// PV as mfma(Vt,P): lane holds O[d=dt*16+hi*4+reg][q=lo].
__global__ __launch_bounds__(256) void attn_mfma(const ushort* __restrict__ qkv,
                                                 const ushort* __restrict__ vt,
                                                 ushort* __restrict__ o) {
    __shared__ char ps[4 * 2048];
    __shared__ float lds_m[4][16], lds_l[4][16];
    __shared__ float lds_o[4][64][16];
    const int tid = threadIdx.x;
    const int wave = tid >> 6, lane = tid & 63;
    const int lo = lane & 15, hi = lane >> 4;
    const int bx = blockIdx.x;
    const int qb = (bx & 1) ? (63 - (bx >> 1)) : (127 - (bx >> 1));  // heavy first
    const int head = blockIdx.y;
    const int bb = blockIdx.z;
    char* psb = ps + wave * 2048;
    const int swz = (lo & 7) << 4;
    const long row0 = (long)bb * SEQ + qb * 16;
    const ushort* Qp = qkv + (row0 + lo) * 2304 + head * 64 + hi * 8;
    bf16x8 qf0 = *(const bf16x8*)Qp;
    bf16x8 qf1 = *(const bf16x8*)(Qp + 32);
    f32x4 oacc[4] = {};
    float m_run = -3.0e38f, l_run = 0.f;
    const ushort* Vbase = vt + (long)(bb * HEADS + head) * 64 * SEQ;

    auto chunk = [&](int base, int valid) {
        const long kr0 = (long)bb * SEQ + base;
        f32x4 s[4] = {};
#pragma unroll
        for (int n = 0; n < 4; ++n) {
            if (n * 16 < valid) {
                const ushort* Kp = qkv + (kr0 + n * 16 + lo) * 2304 + DIM + head * 64 + hi * 8;
                bf16x8 kf0 = *(const bf16x8*)Kp;
                bf16x8 kf1 = *(const bf16x8*)(Kp + 32);
                f32x4 z = {};
                z = MFMA16x32(kf0, qf0, z);
                z = MFMA16x32(kf1, qf1, z);
                s[n] = z;
            }
        }
        float p[4][4];
        float mx = -3.0e38f;
#pragma unroll
        for (int n = 0; n < 4; ++n)
#pragma unroll
            for (int g = 0; g < 4; ++g) {
                float v = (n * 16 < valid) ? s[n][g] * 0.125f : -3.0e38f;
                p[n][g] = v;
                mx = fmaxf(mx, v);
            }
        mx = fmaxf(mx, __shfl_xor(mx, 16, 64));
        mx = fmaxf(mx, __shfl_xor(mx, 32, 64));
        float m_new = fmaxf(m_run, mx);
        float scale = __expf(m_run - m_new);
        float psum = 0.f;
#pragma unroll
        for (int n = 0; n < 4; ++n)
#pragma unroll
            for (int g = 0; g < 4; ++g) {
                float e = __expf(p[n][g] - m_new);
                p[n][g] = e;
                psum += e;
            }
        psum += __shfl_xor(psum, 16, 64);
        psum += __shfl_xor(psum, 32, 64);
        l_run = l_run * scale + psum;
        m_run = m_new;
#pragma unroll
        for (int dt = 0; dt < 4; ++dt) oacc[dt] *= scale;
        // P -> bf16 pairs -> LDS row q=lo (128B rows, XOR-swizzled)
#pragma unroll
        for (int n = 0; n < 4; ++n)
#pragma unroll
            for (int pr = 0; pr < 2; ++pr) {
                uint32_t u = packbf2(p[n][pr * 2], p[n][pr * 2 + 1]);
                *(uint32_t*)(psb + lo * 128 + ((n * 32 + hi * 8 + pr * 4) ^ swz)) = u;
            }
        bf16x8 pa0 = *(const bf16x8*)(psb + lo * 128 + ((hi * 16) ^ swz));
        bf16x8 pa1 = *(const bf16x8*)(psb + lo * 128 + ((64 + hi * 16) ^ swz));
#pragma unroll
        for (int dt = 0; dt < 4; ++dt) {
            const ushort* Vp = Vbase + (long)(dt * 16 + lo) * SEQ + base + hi * 8;
            bf16x8 v0 = *(const bf16x8*)Vp;
            oacc[dt] = MFMA16x32(v0, pa0, oacc[dt]);
            if (valid > 32) {
                bf16x8 v1 = *(const bf16x8*)(Vp + 32);
                oacc[dt] = MFMA16x32(v1, pa1, oacc[dt]);
            }
        }
    };

    const int R = (qb < 64) ? qb * 16 : (qb - 63) * 16;  // second-half run length
    const int Rc = (R + 63) >> 6;
    for (int c = wave; c < Rc; c += 4) chunk(1024 + c * 64, min(64, R - c * 64));
    if (qb < 64 && wave == 3) chunk(qb * 16, 16);

    // ---- merge the 4 wave-partials ----
#pragma unroll
    for (int dt = 0; dt < 4; ++dt)
#pragma unroll
        for (int g = 0; g < 4; ++g) lds_o[wave][dt * 16 + hi * 4 + g][lo] = oacc[dt][g];
    if (hi == 0) { lds_m[wave][lo] = m_run; lds_l[wave][lo] = l_run; }
    __syncthreads();
    float m0 = lds_m[0][lo], m1 = lds_m[1][lo], m2 = lds_m[2][lo], m3 = lds_m[3][lo];
    float mt = fmaxf(fmaxf(m0, m1), fmaxf(m2, m3));
    float f0 = __expf(m0 - mt), f1 = __expf(m1 - mt), f2 = __expf(m2 - mt), f3 = __expf(m3 - mt);
    float lt = lds_l[0][lo] * f0 + lds_l[1][lo] * f1 + lds_l[2][lo] * f2 + lds_l[3][lo] * f3;
    float inv = 1.f / lt;
    ushort4 st;
    float a0, a1c, a2, a3;
    {
        int d = wave * 16 + hi * 4;
        a0 = lds_o[0][d][lo] * f0 + lds_o[1][d][lo] * f1 + lds_o[2][d][lo] * f2 + lds_o[3][d][lo] * f3;
        a1c = lds_o[0][d + 1][lo] * f0 + lds_o[1][d + 1][lo] * f1 + lds_o[2][d + 1][lo] * f2 + lds_o[3][d + 1][lo] * f3;
        a2 = lds_o[0][d + 2][lo] * f0 + lds_o[1][d + 2][lo] * f1 + lds_o[2][d + 2][lo] * f2 + lds_o[3][d + 2][lo] * f3;
        a3 = lds_o[0][d + 3][lo] * f0 + lds_o[1][d + 3][lo] * f1 + lds_o[2][d + 3][lo] * f2 + lds_o[3][d + 3][lo] * f3;
    }
    st.x = f2bf(a0 * inv);
    st.y = f2bf(a1c * inv);
    st.z = f2bf(a2 * inv);
    st.w = f2bf(a3 * inv);
    *(ushort4*)&o[(row0 + lo) * DIM + head * 64 + wave * 16 + hi * 4] = st;
}

extern "C" void kernel_launch(void* const* d_in, const int* in_sizes, int n_in,
                              void* d_out, int out_size, void* d_ws, size_t ws_size,
                              hipStream_t stream) {
    const float* x      = (const float*)d_in[0];
    const float* cosT   = (const float*)d_in[1];
    const float* sinT   = (const float*)d_in[2];
    const float* c      = (const float*)d_in[3];
    const float* W_qkv  = (const float*)d_in[4];
    const float* W_out  = (const float*)d_in[5];
    const float* ln1_w  = (const float*)d_in[6];
    const float* ln2_w  = (const float*)d_in[7];
    const float* mlp_w1 = (const float*)d_in[8];
    const float* mlp_b1 = (const float*)d_in[9];
    const float* mlp_w2 = (const float*)d_in[10];
    const float* mlp_b2 = (const float*)d_in[11];
    const float* ada_w  = (const float*)d_in[12];
    const float* ada_b  = (const float*)d_in[13];
    float* out = (float*)d_out;

    char* ws = (char*)d_ws;
    float*  ada   = (float*)(ws + 0);
    ushort* h     = (ushort*)(ws + 65536L);
    ushort* qkv   = (ushort*)(ws + 6356992L);
    ushort* vt    = (ushort*)(ws + 25231360L);
    ushort* o     = (ushort*)(ws + 31522816L);
    float*  x1    = (float*)(ws + 37814272L);
    ushort* a1    = (ushort*)(ws + 50397184L);
    ushort* wqkvT = (ushort*)(ws + 75563008L);
    ushort* woutT = (ushort*)(ws + 79101952L);
    ushort* w1T   = (ushort*)(ws + 80281600L);
    ushort* w2T   = (ushort*)(ws + 85000192L);

    ada_kernel<<<dim3(18, 2), 256, 0, stream>>>(c, ada_w, ada_b, ada);
    convT<<<dim3(36, 12), 256, 0, stream>>>(W_qkv, wqkvT, 768, 2304);
    convT<<<dim3(12, 12), 256, 0, stream>>>(W_out, woutT, 768, 768);
    convT<<<dim3(48, 12), 256, 0, stream>>>(mlp_w1, w1T, 768, 3072);
    convT<<<dim3(12, 48), 256, 0, stream>>>(mlp_w2, w2T, 3072, 768);

    ln_mod_kernel<<<TOKENS, 256, 0, stream>>>(x, ln1_w, ada, 0, 768, h);
    gemm_bf16<0, 128><<<dim3(18, 32), 256, 0, stream>>>(h, wqkvT, qkv, TOKENS, 2304, 768,
                                                        nullptr, nullptr, nullptr, cosT, sinT);
    vtrans<<<dim3(32, 12, 2), 256, 0, stream>>>(qkv, vt);
    attn_mfma<<<dim3(128, 12, 2), 256, 0, stream>>>(qkv, vt, o);
    gemm_bf16<1, 64><<<dim3(6, 64), 256, 0, stream>>>(o, woutT, x1, TOKENS, 768, 768,
                                                      nullptr, ada + 1536, x, nullptr, nullptr);
    ln_mod_kernel<<<TOKENS, 256, 0, stream>>>(x1, ln2_w, ada, 2304, 3072, h);
    gemm_bf16<2, 128><<<dim3(24, 32), 256, 0, stream>>>(h, w1T, a1, TOKENS, DFF, 768,
                                                        mlp_b1, nullptr, nullptr, nullptr, nullptr);
    gemm_bf16<3, 64><<<dim3(6, 64), 256, 0, stream>>>(a1, w2T, out, TOKENS, 768, DFF,
                                                      mlp_b2, ada + 3840, x1, nullptr, nullptr);
}